// Round 5
// baseline (13.392 us; speedup 1.0000x reference)
//
#include <hip/hip_runtime.h>

#define BATCH  128
#define NB     14
#define TS     1096
#define LTOT   24
#define FRAME  (TS + LTOT - 1)            // 1119
#define OUTLEN ((NB - 1) * TS + FRAME)    // 15367
#define XLEN   (NB * TS)                  // 15344 (flat x per batch)
#define BS     256
#define OPT    4                          // outputs per thread
#define TILE   (BS * OPT)                 // 1024 outputs per block

// Flat formulation: out[b,o] = sum_{j=0..23} xflat[b,o-j] * h[b,(o-j)/TS, j]
// (taps outside [0, XLEN) contribute 0). Block = 1024 consecutive outputs of
// one batch; tap span = 1047 < TS so at most one frame boundary per block.
__global__ __launch_bounds__(256)
void atc_lds4_kernel(const float* __restrict__ x,
                     const float* __restrict__ h,
                     float* __restrict__ out) {
    const int b   = blockIdx.y;
    const int o0  = blockIdx.x * TILE;
    const int tid = threadIdx.x;

    __shared__ __align__(16) float xs[TILE + 32];   // xs[k] = xflat[o0-32+k]
    const float* __restrict__ xb = x + (size_t)b * XLEN;

    // ---- stage 1056 floats = 264 float4 (zero-pad out-of-range) ----
    #pragma unroll
    for (int it = 0; it < 2; ++it) {
        const int idx = tid + it * BS;
        if (idx < (TILE + 32) / 4) {
            const int g = o0 - 32 + 4 * idx;        // 16B-aligned
            float4 v;
            if (g >= 0 && g + 4 <= XLEN) {
                v = *(const float4*)(xb + g);
            } else {
                v.x = ((unsigned)(g+0) < (unsigned)XLEN) ? xb[g+0] : 0.f;
                v.y = ((unsigned)(g+1) < (unsigned)XLEN) ? xb[g+1] : 0.f;
                v.z = ((unsigned)(g+2) < (unsigned)XLEN) ? xb[g+2] : 0.f;
                v.w = ((unsigned)(g+3) < (unsigned)XLEN) ? xb[g+3] : 0.f;
            }
            *(float4*)(&xs[4 * idx]) = v;
        }
    }
    __syncthreads();

    // ---- frame span of this block's valid taps (block-uniform) ----
    int pa = o0 - 23;        if (pa < 0) pa = 0;
    int pb = o0 + TILE - 1;  if (pb > XLEN - 1) pb = XLEN - 1;
    const int fa = pa / TS;
    const int fb = pb / TS;                          // fa or fa+1

    float hwA[LTOT];
    {
        const float* hr = h + ((size_t)b * NB + fa) * LTOT;  // 96B rows, 16B aligned
        #pragma unroll
        for (int q = 0; q < 6; ++q) {
            float4 v = *(const float4*)(hr + 4 * q);
            hwA[4*q] = v.x; hwA[4*q+1] = v.y; hwA[4*q+2] = v.z; hwA[4*q+3] = v.w;
        }
    }

    // ---- sliding window: xw[m] = xs[4*tid+8+m] = xflat[o_t + m - 24] ----
    float xw[28];
    {
        const int base = 4 * tid + 8;                // multiple of 4 -> b128
        #pragma unroll
        for (int q = 0; q < 7; ++q) {
            float4 v = *(const float4*)(&xs[base + 4 * q]);
            xw[4*q] = v.x; xw[4*q+1] = v.y; xw[4*q+2] = v.z; xw[4*q+3] = v.w;
        }
    }

    const int o_t = o0 + 4 * tid;                    // first output of thread
    float acc[OPT] = {0.f, 0.f, 0.f, 0.f};

    if (fa == fb) {
        #pragma unroll
        for (int j = 0; j < LTOT; ++j)
            #pragma unroll
            for (int k = 0; k < OPT; ++k)
                acc[k] = fmaf(hwA[j], xw[24 + k - j], acc[k]);
    } else {
        float hwB[LTOT];
        {
            const float* hr = h + ((size_t)b * NB + fb) * LTOT;
            #pragma unroll
            for (int q = 0; q < 6; ++q) {
                float4 v = *(const float4*)(hr + 4 * q);
                hwB[4*q] = v.x; hwB[4*q+1] = v.y; hwB[4*q+2] = v.z; hwB[4*q+3] = v.w;
            }
        }
        const int sB = fb * TS;
        if (o_t - 23 >= sB || o_t + OPT - 1 < sB) {
            // thread's whole tap window in one frame: single h-row select
            const bool useB = (o_t - 23 >= sB);
            float hw[LTOT];
            #pragma unroll
            for (int j = 0; j < LTOT; ++j) hw[j] = useB ? hwB[j] : hwA[j];
            #pragma unroll
            for (int j = 0; j < LTOT; ++j)
                #pragma unroll
                for (int k = 0; k < OPT; ++k)
                    acc[k] = fmaf(hw[j], xw[24 + k - j], acc[k]);
        } else {
            // window straddles the boundary (~3% of threads in seam blocks)
            #pragma unroll
            for (int j = 0; j < LTOT; ++j)
                #pragma unroll
                for (int k = 0; k < OPT; ++k) {
                    const float hv = (o_t + k - j >= sB) ? hwB[j] : hwA[j];
                    acc[k] = fmaf(hv, xw[24 + k - j], acc[k]);
                }
        }
    }

    // ---- store (per-batch base is odd-word: scalar stores) ----
    float* ob = out + (size_t)b * OUTLEN + o_t;
    if (o_t + OPT - 1 < OUTLEN) {
        #pragma unroll
        for (int k = 0; k < OPT; ++k) ob[k] = acc[k];
    } else {
        #pragma unroll
        for (int k = 0; k < OPT; ++k)
            if (o_t + k < OUTLEN) ob[k] = acc[k];
    }
}

extern "C" void kernel_launch(void* const* d_in, const int* in_sizes, int n_in,
                              void* d_out, int out_size, void* d_ws, size_t ws_size,
                              hipStream_t stream) {
    const float* x = (const float*)d_in[0];   // [B, NB, TS] == [B, XLEN] flat
    const float* h = (const float*)d_in[1];   // [B, NB, LTOT]
    float* out = (float*)d_out;               // [B, OUTLEN]

    dim3 block(BS, 1, 1);
    dim3 grid((OUTLEN + TILE - 1) / TILE, BATCH, 1);   // (16, 128) = 2048 blocks
    atc_lds4_kernel<<<grid, block, 0, stream>>>(x, h, out);
}